// Round 5
// baseline (7858.828 us; speedup 1.0000x reference)
//
#include <hip/hip_runtime.h>

typedef unsigned short u16;
typedef unsigned int u32;

typedef __bf16 bf16x8 __attribute__((ext_vector_type(8)));
typedef float  f32x4  __attribute__((ext_vector_type(4)));

#define N_EMBD 384
#define TT     291
#define NB     128

__device__ __forceinline__ u16 f2bf(float x) {
    union { float f; u32 u; } v; v.f = x;
    u32 r = v.u + 0x7FFFu + ((v.u >> 16) & 1u);
    return (u16)(r >> 16);
}
__device__ __forceinline__ float bfl(u32 u) { return __uint_as_float(u << 16); }
__device__ __forceinline__ float bfh(u32 u) { return __uint_as_float(u & 0xFFFF0000u); }

__device__ __forceinline__ float gelu_f(float x) {
    float u = 0.7978845608028654f * x * (1.f + 0.044715f * x * x);
    float e = __expf(2.f * u);
    float t = 1.f - 2.f / (e + 1.f);   // tanh(u), safe at +-inf
    return 0.5f * x * (1.f + t);
}

// async global->LDS DMA, 16B per lane. LDS dest must be wave-uniform base +
// lane*16 in lane order (m104/m108) — caller guarantees the mapping.
__device__ __forceinline__ void load16_lds(const u16* g, u16* l) {
    __builtin_amdgcn_global_load_lds(
        (const __attribute__((address_space(1))) u32*)g,
        (__attribute__((address_space(3))) u32*)l, 16, 0, 0);
}

// ---------------------------------------------------------------------------
// 32x32 transpose+convert tile body: out[c0+rr][r0+cc] = in[r0+cc][c0+rr]
// ---------------------------------------------------------------------------
__device__ __forceinline__ void tr_tile(const float* __restrict__ src,
                                        u16* __restrict__ dst,
                                        int R, int C, int r0, int c0, int tid) {
    __shared__ float tile[32][33];
    int cc = tid & 31, rr0 = tid >> 5;
#pragma unroll
    for (int s = 0; s < 4; ++s) {
        int rr = rr0 + s * 8;
        tile[rr][cc] = src[(size_t)(r0 + rr) * C + c0 + cc];
    }
    __syncthreads();
#pragma unroll
    for (int s = 0; s < 4; ++s) {
        int rr = rr0 + s * 8;
        dst[(size_t)(c0 + rr) * R + (r0 + cc)] = f2bf(tile[cc][rr]);
    }
}

// generic: in[R][C] f32 -> out[C][R] bf16, grid (C/32, R/32)
__global__ __launch_bounds__(256) void transpose_cvt(const float* __restrict__ in,
                                                     u16* __restrict__ out, int R, int C) {
    tr_tile(in, out, R, C, blockIdx.y * 32, blockIdx.x * 32, threadIdx.x);
}

// fused per-layer weight transpose: all 4 matrices of layer l, grid 1728
__global__ __launch_bounds__(256) void transpose_layer(const float* __restrict__ attn_w,
                                                       const float* __restrict__ proj_w,
                                                       const float* __restrict__ fc_w,
                                                       const float* __restrict__ fc2_w,
                                                       u16* __restrict__ wqkv,
                                                       u16* __restrict__ wproj,
                                                       u16* __restrict__ wfc,
                                                       u16* __restrict__ wfc2t,
                                                       int l) {
    int t = blockIdx.x;
    const float* src; u16* dst; int R, C, tx, ty;
    if (t < 432)       { int i = t;        src = attn_w + (size_t)l * 384 * 1152; dst = wqkv;  R = 384;  C = 1152; tx = i % 36; ty = i / 36; }
    else if (t < 576)  { int i = t - 432;  src = proj_w + (size_t)l * 384 * 384;  dst = wproj; R = 384;  C = 384;  tx = i % 12; ty = i / 12; }
    else if (t < 1152) { int i = t - 576;  src = fc_w   + (size_t)l * 384 * 1536; dst = wfc;   R = 384;  C = 1536; tx = i % 48; ty = i / 48; }
    else               { int i = t - 1152; src = fc2_w  + (size_t)l * 1536 * 384; dst = wfc2t; R = 1536; C = 384;  tx = i % 12; ty = i / 12; }
    tr_tile(src, dst, R, C, ty * 32, tx * 32, threadIdx.x);
}

// ---------------------------------------------------------------------------
// bf16 MFMA GEMM, wide-N tile:  C[M,Ntot] = A[M,K] @ B[K,Ntot]
// Tile 96x384, BK=32, 256 threads (4 waves = 2x2 of 48x192, 3x12 MFMA each).
// A row-major bf16 (row stride lda), BT row-major bf16 [Ntot][ldb].
// Wide N-tile cuts A-refetch (gx) 3x vs 128x128 — staged-traffic bound fix.
// Staging via global_load_lds into unpadded LDS (2-way bank alias = free).
// MODE 0: out bf16 = acc+bias        MODE 1: out bf16 = gelu(acc+bias)
// MODE 2: out f32  = resid+acc+bias  MODE 3: out f32  = acc+bias
// grid (Ntile = spanned cols/384, M/96). out col = blockIdx.x*384 + local.
// ---------------------------------------------------------------------------
template<int MODE>
__global__ __launch_bounds__(256) void gemm_n384(const u16* __restrict__ A, int lda,
                                                 const u16* __restrict__ BT, int ldb,
                                                 const float* __restrict__ bias,
                                                 void* __restrict__ out, int ldc,
                                                 const float* __restrict__ resid,
                                                 int K) {
    __shared__ u16 As[96 * 32];    // 6 KB
    __shared__ u16 Bs[384 * 32];   // 24 KB
    int tid = threadIdx.x;
    int lane = tid & 63, wave = tid >> 6;
    int wr = wave >> 1, wc = wave & 1;
    const u16* Ab = A  + (size_t)blockIdx.y * 96 * lda;
    const u16* Bb = BT + (size_t)blockIdx.x * 384 * ldb;

    f32x4 acc[3][12];
#pragma unroll
    for (int i = 0; i < 3; ++i)
#pragma unroll
        for (int j = 0; j < 12; ++j)
#pragma unroll
            for (int r = 0; r < 4; ++r) acc[i][j][r] = 0.f;

    int r16 = lane & 15;
    int kq  = (lane >> 4) * 8;

    // A: 384 segments of 16B (row=seg>>2, colgrp=seg&3); B: 1536 segments.
    int a_r0 = tid >> 2, a_c0 = (tid & 3) * 8;
    int s1 = 256 + tid;
    int a_r1 = s1 >> 2, a_c1 = (s1 & 3) * 8;
    bool doA1 = tid < 128;   // wave-uniform (waves 0,1)

    for (int kt = 0; kt < K; kt += 32) {
        load16_lds(Ab + (size_t)a_r0 * lda + kt + a_c0, &As[tid * 8]);
        if (doA1) load16_lds(Ab + (size_t)a_r1 * lda + kt + a_c1, &As[s1 * 8]);
#pragma unroll
        for (int s = 0; s < 6; ++s) {
            int seg = s * 256 + tid;
            int br = seg >> 2, bc = (seg & 3) * 8;
            load16_lds(Bb + (size_t)br * ldb + kt + bc, &Bs[seg * 8]);
        }
        __syncthreads();
        bf16x8 af[3];
#pragma unroll
        for (int i = 0; i < 3; ++i)
            af[i] = *(const bf16x8*)&As[(wr * 48 + i * 16 + r16) * 32 + kq];
#pragma unroll
        for (int j = 0; j < 12; ++j) {
            bf16x8 bff = *(const bf16x8*)&Bs[(wc * 192 + j * 16 + r16) * 32 + kq];
#pragma unroll
            for (int i = 0; i < 3; ++i)
                acc[i][j] = __builtin_amdgcn_mfma_f32_16x16x32_bf16(af[i], bff, acc[i][j], 0, 0, 0);
        }
        __syncthreads();
    }

    // epilogue: D row = quad*4 + r, col = lane&15 (m89-verified layout)
    int rbase = (lane >> 4) * 4;
#pragma unroll
    for (int j = 0; j < 12; ++j) {
        int n = blockIdx.x * 384 + wc * 192 + j * 16 + (lane & 15);
        float bj = bias ? bias[n] : 0.f;
#pragma unroll
        for (int i = 0; i < 3; ++i) {
            int gr0 = blockIdx.y * 96 + wr * 48 + i * 16 + rbase;
#pragma unroll
            for (int r = 0; r < 4; ++r) {
                size_t idx = (size_t)(gr0 + r) * ldc + n;
                float v = acc[i][j][r] + bj;
                if (MODE == 0)      ((u16*)out)[idx] = f2bf(v);
                else if (MODE == 1) ((u16*)out)[idx] = f2bf(gelu_f(v));
                else if (MODE == 2) ((float*)out)[idx] = resid[idx] + v;
                else                ((float*)out)[idx] = v;
            }
        }
    }
}

// ---------------------------------------------------------------------------
// LayerNorm: rows of 384 f32 -> 384 (bf16 or f32). block 256 = 4 waves,
// one row per wave. input row = row*inRowMul + inRowAdd, output row = row
// ---------------------------------------------------------------------------
template<bool BF16OUT>
__global__ __launch_bounds__(256) void ln_kernel(const float* __restrict__ x,
                                                 const float* __restrict__ w,
                                                 const float* __restrict__ b,
                                                 void* __restrict__ yout,
                                                 int inRowMul, int inRowAdd, int nRows) {
    int row = blockIdx.x * 4 + (threadIdx.x >> 6);
    if (row >= nRows) return;
    const float* xr = x + ((size_t)row * inRowMul + inRowAdd) * N_EMBD;
    int lane = threadIdx.x & 63;
    float v[6], s = 0.f, s2 = 0.f;
#pragma unroll
    for (int i = 0; i < 6; ++i) {
        v[i] = xr[lane + 64 * i];
        s += v[i]; s2 += v[i] * v[i];
    }
#pragma unroll
    for (int off = 32; off > 0; off >>= 1) {
        s  += __shfl_down(s, off);
        s2 += __shfl_down(s2, off);
    }
    float mean = __shfl(s, 0) * (1.f / 384.f);
    float var  = __shfl(s2, 0) * (1.f / 384.f) - mean * mean;
    float rs = rsqrtf(var + 1e-5f);
#pragma unroll
    for (int i = 0; i < 6; ++i) {
        int c = lane + 64 * i;
        float o = (v[i] - mean) * rs * w[c] + b[c];
        if (BF16OUT) ((u16*)yout)[(size_t)row * N_EMBD + c] = f2bf(o);
        else         ((float*)yout)[(size_t)row * N_EMBD + c] = o;
    }
}

// ---------------------------------------------------------------------------
// MFMA attention. One block (256 thr, 4 waves) per (head, batch).
// qkv bf16 [B*291, 1152] -> o bf16 [B*291, 384].
// Full-row softmax (S=291 -> 19 k-tiles of 16 held in 19 C-frags/wave).
// Rows 0..289 attend to all 291 keys; row 290 attends only to itself.
// ---------------------------------------------------------------------------
__global__ __launch_bounds__(256) void attn_mfma(const u16* __restrict__ qkv,
                                                 u16* __restrict__ o) {
    __shared__ u16 Ks[304][72];
    __shared__ u16 Vt[64][344];
    __shared__ u16 Ps[4][16][344];
    int h = blockIdx.x, b = blockIdx.y;
    int tid = threadIdx.x;
    int lane = tid & 63, wave = tid >> 6;
    int ln = lane & 15, quad = lane >> 4;
    const u16* base = qkv + (size_t)b * TT * 1152;

    // ---- stage K rows 0..290 (+zero pad rows 291..303) ----
    for (int slot = tid; slot < 304 * 8; slot += 256) {
        int row = slot >> 3, seg = slot & 7;
        uint4 v = make_uint4(0, 0, 0, 0);
        if (row < TT) v = *(const uint4*)(base + (size_t)row * 1152 + 384 + h * 64 + seg * 8);
        *(uint4*)&Ks[row][seg * 8] = v;
    }
    // ---- stage V transposed: Vt[d][key] ----
    for (int slot = tid; slot < TT * 8; slot += 256) {
        int dg = slot / TT, k = slot - dg * TT;
        uint4 v = *(const uint4*)(base + (size_t)k * 1152 + 768 + h * 64 + dg * 8);
        const u16* pv = (const u16*)&v;
#pragma unroll
        for (int j = 0; j < 8; ++j) Vt[dg * 8 + j][k] = pv[j];
    }
    // zero pad cols 291..319 of Vt
    for (int slot = tid; slot < 64 * 32; slot += 256) {
        int d = slot >> 5, c = 288 + (slot & 31);
        if (c >= TT && c < 320) Vt[d][c] = 0;
    }
    __syncthreads();

    // ---- per-wave Q-tiles ----
    for (int qt = wave; qt < 19; qt += 4) {
        int q0 = qt * 16;
        int qrow = q0 + ln; if (qrow > TT - 1) qrow = TT - 1;
        const u16* qp = base + (size_t)qrow * 1152 + h * 64;
        bf16x8 qf0 = *(const bf16x8*)(qp + quad * 8);
        bf16x8 qf1 = *(const bf16x8*)(qp + 32 + quad * 8);

        f32x4 sc[19];
#pragma unroll
        for (int kt = 0; kt < 19; ++kt) {
            bf16x8 kb0 = *(const bf16x8*)&Ks[kt * 16 + ln][quad * 8];
            bf16x8 kb1 = *(const bf16x8*)&Ks[kt * 16 + ln][32 + quad * 8];
            f32x4 z = {0.f, 0.f, 0.f, 0.f};
            z = __builtin_amdgcn_mfma_f32_16x16x32_bf16(qf0, kb0, z, 0, 0, 0);
            sc[kt] = __builtin_amdgcn_mfma_f32_16x16x32_bf16(qf1, kb1, z, 0, 0, 0);
        }

        float linv[4];
#pragma unroll
        for (int r = 0; r < 4; ++r) {
            int q = q0 + quad * 4 + r;
            float m = -1e30f;
#pragma unroll
            for (int kt = 0; kt < 19; ++kt) {
                int key = kt * 16 + ln;
                float s = sc[kt][r] * 0.125f;
                bool ok = (key < TT) && (q != TT - 1 || key == TT - 1);
                s = ok ? s : -1e30f;
                sc[kt][r] = s;
                m = fmaxf(m, s);
            }
            m = fmaxf(m, __shfl_xor(m, 1));
            m = fmaxf(m, __shfl_xor(m, 2));
            m = fmaxf(m, __shfl_xor(m, 4));
            m = fmaxf(m, __shfl_xor(m, 8));
            float l = 0.f;
#pragma unroll
            for (int kt = 0; kt < 19; ++kt) {
                float p = __expf(sc[kt][r] - m);
                sc[kt][r] = p;
                l += p;
            }
            l += __shfl_xor(l, 1);
            l += __shfl_xor(l, 2);
            l += __shfl_xor(l, 4);
            l += __shfl_xor(l, 8);
            linv[r] = 1.f / l;
        }

#pragma unroll
        for (int kt = 0; kt < 19; ++kt) {
#pragma unroll
            for (int r = 0; r < 4; ++r)
                Ps[wave][quad * 4 + r][kt * 16 + ln] = f2bf(sc[kt][r]);
        }
#pragma unroll
        for (int r = 0; r < 4; ++r) Ps[wave][quad * 4 + r][304 + ln] = 0;

        f32x4 of[4];
#pragma unroll
        for (int nt = 0; nt < 4; ++nt)
#pragma unroll
            for (int r = 0; r < 4; ++r) of[nt][r] = 0.f;
#pragma unroll
        for (int kt2 = 0; kt2 < 10; ++kt2) {
            bf16x8 pa = *(const bf16x8*)&Ps[wave][ln][kt2 * 32 + quad * 8];
#pragma unroll
            for (int nt = 0; nt < 4; ++nt) {
                bf16x8 vb = *(const bf16x8*)&Vt[nt * 16 + ln][kt2 * 32 + quad * 8];
                of[nt] = __builtin_amdgcn_mfma_f32_16x16x32_bf16(pa, vb, of[nt], 0, 0, 0);
            }
        }

#pragma unroll
        for (int nt = 0; nt < 4; ++nt) {
#pragma unroll
            for (int r = 0; r < 4; ++r) {
                int q = q0 + quad * 4 + r;
                if (q < TT)
                    o[((size_t)(b * TT + q)) * N_EMBD + h * 64 + nt * 16 + ln] =
                        f2bf(of[nt][r] * linv[r]);
            }
        }
    }
}

// ---------------------------------------------------------------------------
// Tokenizer helpers
// ---------------------------------------------------------------------------
__global__ __launch_bounds__(256) void patchify_kernel(const float* __restrict__ images,
                                                       u16* __restrict__ P) {
    int idx = blockIdx.x * 256 + threadIdx.x;  // 36864*192 exact
    int col = idx % 192, row = idx / 192;
    int p = row % 144, bt = row / 144;
    int c = col % 3, pp = col / 3;
    int pw = pp & 7, ph = pp >> 3;
    int hp = p / 12, wp = p % 12;
    float v = images[(((size_t)bt * 3 + c) * 96 + hp * 8 + ph) * 96 + wp * 8 + pw];
    P[idx] = f2bf(v);
}

__global__ __launch_bounds__(256) void img_scatter_kernel(const float* __restrict__ imgtok,
                                                          const float* __restrict__ temb,
                                                          const float* __restrict__ pos,
                                                          float* __restrict__ xw) {
    int idx = blockIdx.x * 256 + threadIdx.x;  // 36864*384 exact
    int n = idx % 384, row = idx / 384;
    int p = row % 144, bt = row / 144;
    int t = bt & 1, b = bt >> 1;
    int tok = t * 145 + 1 + p;
    xw[((size_t)b * TT + tok) * N_EMBD + n] =
        imgtok[idx] + temb[t * N_EMBD + n] + pos[(size_t)tok * N_EMBD + n];
}

__global__ __launch_bounds__(384) void st_kernel(const float* __restrict__ state,
                                                 const float* __restrict__ w1,
                                                 const float* __restrict__ b1,
                                                 const float* __restrict__ w2,
                                                 const float* __restrict__ b2,
                                                 const float* __restrict__ temb,
                                                 const float* __restrict__ pos,
                                                 float* __restrict__ xw) {
    int bt = blockIdx.x;
    int t = bt & 1, b = bt >> 1;
    int n = threadIdx.x;
    float s0 = state[bt * 2], s1 = state[bt * 2 + 1];
    float acc = b2[n];
#pragma unroll
    for (int j = 0; j < 32; ++j) {
        float hh = fmaxf(s0 * w1[j] + s1 * w1[32 + j] + b1[j], 0.f);
        acc += hh * w2[j * N_EMBD + n];
    }
    int tok = t * 145;
    xw[((size_t)b * TT + tok) * N_EMBD + n] =
        acc + temb[t * N_EMBD + n] + pos[(size_t)tok * N_EMBD + n];
}

__global__ __launch_bounds__(256) void ro_kernel(const float* __restrict__ readout,
                                                 const float* __restrict__ pos,
                                                 float* __restrict__ xw) {
    int idx = blockIdx.x * 256 + threadIdx.x;  // 128*384 exact
    int n = idx % 384, b = idx / 384;
    xw[((size_t)b * TT + 290) * N_EMBD + n] = readout[n] + pos[(size_t)290 * N_EMBD + n];
}

// ---------------------------------------------------------------------------
// Workspace layout (all offsets 256B-aligned). TOTAL = 175,325,184 B (~167 MB)
// ---------------------------------------------------------------------------
extern "C" void kernel_launch(void* const* d_in, const int* in_sizes, int n_in,
                              void* d_out, int out_size, void* d_ws, size_t ws_size,
                              hipStream_t stream) {
    const float* images   = (const float*)d_in[0];
    const float* state    = (const float*)d_in[1];
    const float* img_w    = (const float*)d_in[2];
    const float* img_b    = (const float*)d_in[3];
    const float* img_temb = (const float*)d_in[4];
    const float* st_w1    = (const float*)d_in[5];
    const float* st_b1    = (const float*)d_in[6];
    const float* st_w2    = (const float*)d_in[7];
    const float* st_b2    = (const float*)d_in[8];
    const float* st_temb  = (const float*)d_in[9];
    const float* readout  = (const float*)d_in[10];
    const float* pos      = (const float*)d_in[11];
    const float* ln1_w    = (const float*)d_in[12];
    const float* ln1_b    = (const float*)d_in[13];
    const float* attn_w   = (const float*)d_in[14];
    const float* attn_b   = (const float*)d_in[15];
    const float* proj_w   = (const float*)d_in[16];
    const float* proj_b   = (const float*)d_in[17];
    const float* ln2_w    = (const float*)d_in[18];
    const float* ln2_b    = (const float*)d_in[19];
    const float* fc_w     = (const float*)d_in[20];
    const float* fc_b     = (const float*)d_in[21];
    const float* fc2_w    = (const float*)d_in[22];
    const float* fc2_b    = (const float*)d_in[23];
    const float* lnf_w    = (const float*)d_in[24];
    const float* lnf_b    = (const float*)d_in[25];

    char* ws = (char*)d_ws;
    float* XW   = (float*)(ws);
    u16*   Y    = (u16*)(ws + 57212928ull);       // also O (attn output)
    u16*   SH   = (u16*)(ws + 85819392ull);       // QKV | G | setup
    u16*   QKV  = SH;
    u16*   G    = SH;
    u16*   P    = SH;                              // setup: patches [36864,192]
    float* IMGT = (float*)(ws + 85819392ull + 14155776ull);  // setup: [36864,384] f32
    u16*   WQKVl  = (u16*)(ws + 171638784ull);    // [1152][384]
    u16*   WPROJl = (u16*)(ws + 172523520ull);    // [384][384]
    u16*   WFCl   = (u16*)(ws + 172818432ull);    // [1536][384]
    u16*   WFC2Tl = (u16*)(ws + 173998080ull);    // [384][1536]
    u16*   WIMG   = (u16*)(ws + 175177728ull);    // [384][192]

    // ---- tokenizers -> XW [128*291, 384] f32 ----
    transpose_cvt<<<dim3(12, 6), 256, 0, stream>>>(img_w, WIMG, 192, 384);
    patchify_kernel<<<27648, 256, 0, stream>>>(images, P);
    gemm_n384<3><<<dim3(1, 384), 256, 0, stream>>>(P, 192, WIMG, 192, img_b,
                                                   IMGT, 384, nullptr, 192);
    img_scatter_kernel<<<55296, 256, 0, stream>>>(IMGT, img_temb, pos, XW);
    st_kernel<<<256, 384, 0, stream>>>(state, st_w1, st_b1, st_w2, st_b2, st_temb, pos, XW);
    ro_kernel<<<192, 256, 0, stream>>>(readout, pos, XW);

    // ---- transformer layers (M = 37248 = 96 * 388) ----
    for (int l = 0; l < 12; ++l) {
        transpose_layer<<<1728, 256, 0, stream>>>(attn_w, proj_w, fc_w, fc2_w,
                                                  WQKVl, WPROJl, WFCl, WFC2Tl, l);
        ln_kernel<true><<<9312, 256, 0, stream>>>(XW, ln1_w + l * 384, ln1_b + l * 384, Y, 1, 0, 37248);
        gemm_n384<0><<<dim3(3, 388), 256, 0, stream>>>(Y, 384, WQKVl, 384,
                                                       attn_b + l * 1152, QKV, 1152, nullptr, 384);
        attn_mfma<<<dim3(6, 128), 256, 0, stream>>>(QKV, Y);   // O aliases Y
        gemm_n384<2><<<dim3(1, 388), 256, 0, stream>>>(Y, 384, WPROJl, 384,
                                                       proj_b + l * 384, XW, 384, XW, 384);
        ln_kernel<true><<<9312, 256, 0, stream>>>(XW, ln2_w + l * 384, ln2_b + l * 384, Y, 1, 0, 37248);
        // MLP in two 768-wide halves so G fits in the QKV region
        gemm_n384<1><<<dim3(2, 388), 256, 0, stream>>>(Y, 384, WFCl, 384,
                                                       fc_b + l * 1536, G, 768, nullptr, 384);
        gemm_n384<2><<<dim3(1, 388), 256, 0, stream>>>(G, 768, WFC2Tl, 1536,
                                                       nullptr, XW, 384, XW, 768);
        gemm_n384<1><<<dim3(2, 388), 256, 0, stream>>>(Y, 384, WFCl + 768 * 384, 384,
                                                       fc_b + l * 1536 + 768, G, 768, nullptr, 384);
        gemm_n384<2><<<dim3(1, 388), 256, 0, stream>>>(G, 768, WFC2Tl + 768, 1536,
                                                       fc2_b + l * 384, XW, 384, XW, 768);
    }
    // final LN on readout rows -> d_out [128, 384] f32
    ln_kernel<false><<<32, 256, 0, stream>>>(XW, lnf_w, lnf_b, d_out, TT, 290, 128);
}

// Round 6
// 7708.578 us; speedup vs baseline: 1.0195x; 1.0195x over previous
//
#include <hip/hip_runtime.h>

typedef unsigned short u16;
typedef unsigned int u32;

typedef __bf16 bf16x8 __attribute__((ext_vector_type(8)));
typedef float  f32x4  __attribute__((ext_vector_type(4)));

#define N_EMBD 384
#define TT     291
#define NB     128

__device__ __forceinline__ u16 f2bf(float x) {
    union { float f; u32 u; } v; v.f = x;
    u32 r = v.u + 0x7FFFu + ((v.u >> 16) & 1u);
    return (u16)(r >> 16);
}
__device__ __forceinline__ float bfl(u32 u) { return __uint_as_float(u << 16); }
__device__ __forceinline__ float bfh(u32 u) { return __uint_as_float(u & 0xFFFF0000u); }

__device__ __forceinline__ float gelu_f(float x) {
    float u = 0.7978845608028654f * x * (1.f + 0.044715f * x * x);
    float e = __expf(2.f * u);
    float t = 1.f - 2.f / (e + 1.f);   // tanh(u), safe at +-inf
    return 0.5f * x * (1.f + t);
}

// async global->LDS DMA, 16B per lane. LDS dest must be wave-uniform base +
// lane*16 in lane order (m104/m108) — caller guarantees the mapping.
__device__ __forceinline__ void load16_lds(const u16* g, u16* l) {
    __builtin_amdgcn_global_load_lds(
        (const __attribute__((address_space(1))) u32*)g,
        (__attribute__((address_space(3))) u32*)l, 16, 0, 0);
}

// ---------------------------------------------------------------------------
// 32x32 transpose+convert tile body: out[c0+rr][r0+cc] = in[r0+cc][c0+rr]
// ---------------------------------------------------------------------------
__device__ __forceinline__ void tr_tile(const float* __restrict__ src,
                                        u16* __restrict__ dst,
                                        int R, int C, int r0, int c0, int tid) {
    __shared__ float tile[32][33];
    int cc = tid & 31, rr0 = tid >> 5;
#pragma unroll
    for (int s = 0; s < 4; ++s) {
        int rr = rr0 + s * 8;
        tile[rr][cc] = src[(size_t)(r0 + rr) * C + c0 + cc];
    }
    __syncthreads();
#pragma unroll
    for (int s = 0; s < 4; ++s) {
        int rr = rr0 + s * 8;
        dst[(size_t)(c0 + rr) * R + (r0 + cc)] = f2bf(tile[cc][rr]);
    }
}

// generic: in[R][C] f32 -> out[C][R] bf16, grid (C/32, R/32)
__global__ __launch_bounds__(256) void transpose_cvt(const float* __restrict__ in,
                                                     u16* __restrict__ out, int R, int C) {
    tr_tile(in, out, R, C, blockIdx.y * 32, blockIdx.x * 32, threadIdx.x);
}

// fused per-layer weight transpose: all 4 matrices of layer l, grid 1728
__global__ __launch_bounds__(256) void transpose_layer(const float* __restrict__ attn_w,
                                                       const float* __restrict__ proj_w,
                                                       const float* __restrict__ fc_w,
                                                       const float* __restrict__ fc2_w,
                                                       u16* __restrict__ wqkv,
                                                       u16* __restrict__ wproj,
                                                       u16* __restrict__ wfc,
                                                       u16* __restrict__ wfc2t,
                                                       int l) {
    int t = blockIdx.x;
    const float* src; u16* dst; int R, C, tx, ty;
    if (t < 432)       { int i = t;        src = attn_w + (size_t)l * 384 * 1152; dst = wqkv;  R = 384;  C = 1152; tx = i % 36; ty = i / 36; }
    else if (t < 576)  { int i = t - 432;  src = proj_w + (size_t)l * 384 * 384;  dst = wproj; R = 384;  C = 384;  tx = i % 12; ty = i / 12; }
    else if (t < 1152) { int i = t - 576;  src = fc_w   + (size_t)l * 384 * 1536; dst = wfc;   R = 384;  C = 1536; tx = i % 48; ty = i / 48; }
    else               { int i = t - 1152; src = fc2_w  + (size_t)l * 1536 * 384; dst = wfc2t; R = 1536; C = 384;  tx = i % 12; ty = i / 12; }
    tr_tile(src, dst, R, C, ty * 32, tx * 32, threadIdx.x);
}

// ---------------------------------------------------------------------------
// bf16 MFMA GEMM (round-4 known-good):  C[M,N] = A[M,K] @ B[K,N]
// A row-major bf16 (row stride K), BT row-major bf16 [N][ldb] (B^T slice).
// Tile 128x128, BK=32, 256 threads (4 waves = 2x2 of 64x64, each 4x4 MFMA).
// MODE 0: out bf16 = acc+bias        MODE 1: out bf16 = gelu(acc+bias)
// MODE 2: out f32  = resid+acc+bias  MODE 3: out f32  = acc+bias
// out row stride = N. grid (N/128, M/128)
// ---------------------------------------------------------------------------
template<int MODE>
__global__ __launch_bounds__(256) void gemm_bt(const u16* __restrict__ A,
                                               const u16* __restrict__ BT, int ldb,
                                               const float* __restrict__ bias,
                                               void* __restrict__ out,
                                               const float* __restrict__ resid,
                                               int N, int K) {
    __shared__ u16 As[128 * 32];
    __shared__ u16 Bs[128 * 32];
    int tid = threadIdx.x;
    int lane = tid & 63, wave = tid >> 6;
    int wr = wave >> 1, wc = wave & 1;
    const u16* Ab = A  + (size_t)blockIdx.y * 128 * K;
    const u16* Bb = BT + (size_t)blockIdx.x * 128 * ldb;

    f32x4 acc[4][4];
#pragma unroll
    for (int i = 0; i < 4; ++i)
#pragma unroll
        for (int j = 0; j < 4; ++j)
#pragma unroll
            for (int r = 0; r < 4; ++r) acc[i][j][r] = 0.f;

    int r16 = lane & 15;
    int kq  = (lane >> 4) * 8;

    int seg0 = tid, seg1 = 256 + tid;
    int ar0 = seg0 >> 2, ac0 = (seg0 & 3) * 8;
    int ar1 = seg1 >> 2, ac1 = (seg1 & 3) * 8;

    for (int kt = 0; kt < K; kt += 32) {
        load16_lds(Ab + (size_t)ar0 * K + kt + ac0, &As[seg0 * 8]);
        load16_lds(Ab + (size_t)ar1 * K + kt + ac1, &As[seg1 * 8]);
        load16_lds(Bb + (size_t)ar0 * ldb + kt + ac0, &Bs[seg0 * 8]);
        load16_lds(Bb + (size_t)ar1 * ldb + kt + ac1, &Bs[seg1 * 8]);
        __syncthreads();
        bf16x8 af[4], bff[4];
#pragma unroll
        for (int i = 0; i < 4; ++i) {
            af[i]  = *(const bf16x8*)&As[(wr * 64 + i * 16 + r16) * 32 + kq];
            bff[i] = *(const bf16x8*)&Bs[(wc * 64 + i * 16 + r16) * 32 + kq];
        }
#pragma unroll
        for (int i = 0; i < 4; ++i)
#pragma unroll
            for (int j = 0; j < 4; ++j)
                acc[i][j] = __builtin_amdgcn_mfma_f32_16x16x32_bf16(af[i], bff[j], acc[i][j], 0, 0, 0);
        __syncthreads();
    }

    int rbase = (lane >> 4) * 4;
#pragma unroll
    for (int i = 0; i < 4; ++i) {
#pragma unroll
        for (int j = 0; j < 4; ++j) {
            int gr0 = blockIdx.y * 128 + wr * 64 + i * 16 + rbase;
            int gc  = blockIdx.x * 128 + wc * 64 + j * 16 + (lane & 15);
            float bj = bias ? bias[gc] : 0.f;
#pragma unroll
            for (int r = 0; r < 4; ++r) {
                size_t idx = (size_t)(gr0 + r) * N + gc;
                float v = acc[i][j][r] + bj;
                if (MODE == 0)      ((u16*)out)[idx] = f2bf(v);
                else if (MODE == 1) ((u16*)out)[idx] = f2bf(gelu_f(v));
                else if (MODE == 2) ((float*)out)[idx] = resid[idx] + v;
                else                ((float*)out)[idx] = v;
            }
        }
    }
}

// ---------------------------------------------------------------------------
// Fused MLP:  XW += gelu(Y @ W1 + b1) @ W2 + b2     (G never hits global)
// One block = 64 rows. grid 582. 8 chunks of 192 G-cols:
//   FC1-chunk (K=384) -> gelu -> G-chunk LDS (C-layout write / A-frag read,
//   the attn-verified round-trip; stride 200 u16 = 400B, 16B-aligned) ->
//   FC2 partial (K=192) accumulated into persistent acc2 (wave = 32x192).
// W1T [1536][384], W2T [384][1536], both B^T row-major bf16.
// ---------------------------------------------------------------------------
__global__ __launch_bounds__(256) void fc_fused(const u16* __restrict__ Y,
                                                const u16* __restrict__ W1T,
                                                const float* __restrict__ b1,
                                                const u16* __restrict__ W2T,
                                                const float* __restrict__ b2,
                                                float* __restrict__ XW) {
    __shared__ u16 As[64 * 32];     //  4 KB
    __shared__ u16 Bs1[192 * 32];   // 12 KB
    __shared__ u16 Bs2[384 * 32];   // 24 KB
    __shared__ u16 Gc[64 * 200];    // 25.6 KB (stride 200 u16: 2-way banks, 16B aligned)
    int tid = threadIdx.x;
    int lane = tid & 63, wave = tid >> 6;
    int ln = lane & 15, quad = lane >> 4;
    int wr2 = wave >> 1, wc2 = wave & 1;
    const u16* Yb = Y + (size_t)blockIdx.x * 64 * 384;

    f32x4 acc2[2][12];
#pragma unroll
    for (int i = 0; i < 2; ++i)
#pragma unroll
        for (int j = 0; j < 12; ++j)
#pragma unroll
            for (int r = 0; r < 4; ++r) acc2[i][j][r] = 0.f;

    for (int c = 0; c < 8; ++c) {
        const u16* W1c = W1T + (size_t)(c * 192) * 384;
        f32x4 acc1[4][3];
#pragma unroll
        for (int i = 0; i < 4; ++i)
#pragma unroll
            for (int j = 0; j < 3; ++j)
#pragma unroll
                for (int r = 0; r < 4; ++r) acc1[i][j][r] = 0.f;

        // ---- FC1 chunk: 64 x 192, K = 384 ----
        for (int kt = 0; kt < 384; kt += 32) {
            // As: 256 segs (1/thread)
            load16_lds(Yb + (size_t)(tid >> 2) * 384 + kt + (tid & 3) * 8, &As[tid * 8]);
            // Bs1: 768 segs (3/thread)
#pragma unroll
            for (int s = 0; s < 3; ++s) {
                int seg = s * 256 + tid;
                load16_lds(W1c + (size_t)(seg >> 2) * 384 + kt + (seg & 3) * 8, &Bs1[seg * 8]);
            }
            __syncthreads();
            bf16x8 af[4];
#pragma unroll
            for (int i = 0; i < 4; ++i)
                af[i] = *(const bf16x8*)&As[(i * 16 + ln) * 32 + quad * 8];
#pragma unroll
            for (int j = 0; j < 3; ++j) {
                bf16x8 bff = *(const bf16x8*)&Bs1[(wave * 48 + j * 16 + ln) * 32 + quad * 8];
#pragma unroll
                for (int i = 0; i < 4; ++i)
                    acc1[i][j] = __builtin_amdgcn_mfma_f32_16x16x32_bf16(af[i], bff, acc1[i][j], 0, 0, 0);
            }
            __syncthreads();
        }

        // ---- gelu + write G chunk to LDS (C-layout: row = quad*4+r, col = ln) ----
#pragma unroll
        for (int j = 0; j < 3; ++j) {
            int col = wave * 48 + j * 16 + ln;
            float bb = b1[c * 192 + col];
#pragma unroll
            for (int i = 0; i < 4; ++i)
#pragma unroll
                for (int r = 0; r < 4; ++r)
                    Gc[(i * 16 + quad * 4 + r) * 200 + col] = f2bf(gelu_f(acc1[i][j][r] + bb));
        }
        __syncthreads();

        // ---- FC2 partial: acc2 += G_chunk @ W2[c*192 .. +192, :] ----
        const u16* W2c = W2T + c * 192;
        for (int kt2 = 0; kt2 < 192; kt2 += 32) {
            // Bs2: 1536 segs (6/thread)
#pragma unroll
            for (int s = 0; s < 6; ++s) {
                int seg = s * 256 + tid;
                load16_lds(W2c + (size_t)(seg >> 2) * 1536 + kt2 + (seg & 3) * 8, &Bs2[seg * 8]);
            }
            __syncthreads();
            bf16x8 a2[2];
#pragma unroll
            for (int i = 0; i < 2; ++i)
                a2[i] = *(const bf16x8*)&Gc[(wr2 * 32 + i * 16 + ln) * 200 + kt2 + quad * 8];
#pragma unroll
            for (int j = 0; j < 12; ++j) {
                bf16x8 bf2 = *(const bf16x8*)&Bs2[(wc2 * 192 + j * 16 + ln) * 32 + quad * 8];
#pragma unroll
                for (int i = 0; i < 2; ++i)
                    acc2[i][j] = __builtin_amdgcn_mfma_f32_16x16x32_bf16(a2[i], bf2, acc2[i][j], 0, 0, 0);
            }
            __syncthreads();
        }
    }

    // ---- epilogue: XW += acc2 + b2 ----
#pragma unroll
    for (int j = 0; j < 12; ++j) {
        int col = wc2 * 192 + j * 16 + ln;
        float bb = b2[col];
#pragma unroll
        for (int i = 0; i < 2; ++i) {
            int gr0 = blockIdx.x * 64 + wr2 * 32 + i * 16 + quad * 4;
#pragma unroll
            for (int r = 0; r < 4; ++r) {
                size_t idx = (size_t)(gr0 + r) * 384 + col;
                XW[idx] = XW[idx] + acc2[i][j][r] + bb;
            }
        }
    }
}

// ---------------------------------------------------------------------------
// LayerNorm: rows of 384 f32 -> 384 (bf16 or f32). block 256 = 4 waves,
// one row per wave. input row = row*inRowMul + inRowAdd, output row = row
// ---------------------------------------------------------------------------
template<bool BF16OUT>
__global__ __launch_bounds__(256) void ln_kernel(const float* __restrict__ x,
                                                 const float* __restrict__ w,
                                                 const float* __restrict__ b,
                                                 void* __restrict__ yout,
                                                 int inRowMul, int inRowAdd, int nRows) {
    int row = blockIdx.x * 4 + (threadIdx.x >> 6);
    if (row >= nRows) return;
    const float* xr = x + ((size_t)row * inRowMul + inRowAdd) * N_EMBD;
    int lane = threadIdx.x & 63;
    float v[6], s = 0.f, s2 = 0.f;
#pragma unroll
    for (int i = 0; i < 6; ++i) {
        v[i] = xr[lane + 64 * i];
        s += v[i]; s2 += v[i] * v[i];
    }
#pragma unroll
    for (int off = 32; off > 0; off >>= 1) {
        s  += __shfl_down(s, off);
        s2 += __shfl_down(s2, off);
    }
    float mean = __shfl(s, 0) * (1.f / 384.f);
    float var  = __shfl(s2, 0) * (1.f / 384.f) - mean * mean;
    float rs = rsqrtf(var + 1e-5f);
#pragma unroll
    for (int i = 0; i < 6; ++i) {
        int c = lane + 64 * i;
        float o = (v[i] - mean) * rs * w[c] + b[c];
        if (BF16OUT) ((u16*)yout)[(size_t)row * N_EMBD + c] = f2bf(o);
        else         ((float*)yout)[(size_t)row * N_EMBD + c] = o;
    }
}

// ---------------------------------------------------------------------------
// MFMA attention. One block (256 thr, 4 waves) per (head, batch).
// qkv bf16 [B*291, 1152] -> o bf16 [B*291, 384].
// Full-row softmax (S=291 -> 19 k-tiles of 16 held in 19 C-frags/wave).
// Rows 0..289 attend to all 291 keys; row 290 attends only to itself.
// ---------------------------------------------------------------------------
__global__ __launch_bounds__(256) void attn_mfma(const u16* __restrict__ qkv,
                                                 u16* __restrict__ o) {
    __shared__ u16 Ks[304][72];
    __shared__ u16 Vt[64][344];
    __shared__ u16 Ps[4][16][344];
    int h = blockIdx.x, b = blockIdx.y;
    int tid = threadIdx.x;
    int lane = tid & 63, wave = tid >> 6;
    int ln = lane & 15, quad = lane >> 4;
    const u16* base = qkv + (size_t)b * TT * 1152;

    // ---- stage K rows 0..290 (+zero pad rows 291..303) ----
    for (int slot = tid; slot < 304 * 8; slot += 256) {
        int row = slot >> 3, seg = slot & 7;
        uint4 v = make_uint4(0, 0, 0, 0);
        if (row < TT) v = *(const uint4*)(base + (size_t)row * 1152 + 384 + h * 64 + seg * 8);
        *(uint4*)&Ks[row][seg * 8] = v;
    }
    // ---- stage V transposed: Vt[d][key] ----
    for (int slot = tid; slot < TT * 8; slot += 256) {
        int dg = slot / TT, k = slot - dg * TT;
        uint4 v = *(const uint4*)(base + (size_t)k * 1152 + 768 + h * 64 + dg * 8);
        const u16* pv = (const u16*)&v;
#pragma unroll
        for (int j = 0; j < 8; ++j) Vt[dg * 8 + j][k] = pv[j];
    }
    // zero pad cols 291..319 of Vt
    for (int slot = tid; slot < 64 * 32; slot += 256) {
        int d = slot >> 5, c = 288 + (slot & 31);
        if (c >= TT && c < 320) Vt[d][c] = 0;
    }
    __syncthreads();

    // ---- per-wave Q-tiles ----
    for (int qt = wave; qt < 19; qt += 4) {
        int q0 = qt * 16;
        int qrow = q0 + ln; if (qrow > TT - 1) qrow = TT - 1;
        const u16* qp = base + (size_t)qrow * 1152 + h * 64;
        bf16x8 qf0 = *(const bf16x8*)(qp + quad * 8);
        bf16x8 qf1 = *(const bf16x8*)(qp + 32 + quad * 8);

        f32x4 sc[19];
#pragma unroll
        for (int kt = 0; kt < 19; ++kt) {
            bf16x8 kb0 = *(const bf16x8*)&Ks[kt * 16 + ln][quad * 8];
            bf16x8 kb1 = *(const bf16x8*)&Ks[kt * 16 + ln][32 + quad * 8];
            f32x4 z = {0.f, 0.f, 0.f, 0.f};
            z = __builtin_amdgcn_mfma_f32_16x16x32_bf16(qf0, kb0, z, 0, 0, 0);
            sc[kt] = __builtin_amdgcn_mfma_f32_16x16x32_bf16(qf1, kb1, z, 0, 0, 0);
        }

        float linv[4];
#pragma unroll
        for (int r = 0; r < 4; ++r) {
            int q = q0 + quad * 4 + r;
            float m = -1e30f;
#pragma unroll
            for (int kt = 0; kt < 19; ++kt) {
                int key = kt * 16 + ln;
                float s = sc[kt][r] * 0.125f;
                bool ok = (key < TT) && (q != TT - 1 || key == TT - 1);
                s = ok ? s : -1e30f;
                sc[kt][r] = s;
                m = fmaxf(m, s);
            }
            m = fmaxf(m, __shfl_xor(m, 1));
            m = fmaxf(m, __shfl_xor(m, 2));
            m = fmaxf(m, __shfl_xor(m, 4));
            m = fmaxf(m, __shfl_xor(m, 8));
            float l = 0.f;
#pragma unroll
            for (int kt = 0; kt < 19; ++kt) {
                float p = __expf(sc[kt][r] - m);
                sc[kt][r] = p;
                l += p;
            }
            l += __shfl_xor(l, 1);
            l += __shfl_xor(l, 2);
            l += __shfl_xor(l, 4);
            l += __shfl_xor(l, 8);
            linv[r] = 1.f / l;
        }

#pragma unroll
        for (int kt = 0; kt < 19; ++kt) {
#pragma unroll
            for (int r = 0; r < 4; ++r)
                Ps[wave][quad * 4 + r][kt * 16 + ln] = f2bf(sc[kt][r]);
        }
#pragma unroll
        for (int r = 0; r < 4; ++r) Ps[wave][quad * 4 + r][304 + ln] = 0;

        f32x4 of[4];
#pragma unroll
        for (int nt = 0; nt < 4; ++nt)
#pragma unroll
            for (int r = 0; r < 4; ++r) of[nt][r] = 0.f;
#pragma unroll
        for (int kt2 = 0; kt2 < 10; ++kt2) {
            bf16x8 pa = *(const bf16x8*)&Ps[wave][ln][kt2 * 32 + quad * 8];
#pragma unroll
            for (int nt = 0; nt < 4; ++nt) {
                bf16x8 vb = *(const bf16x8*)&Vt[nt * 16 + ln][kt2 * 32 + quad * 8];
                of[nt] = __builtin_amdgcn_mfma_f32_16x16x32_bf16(pa, vb, of[nt], 0, 0, 0);
            }
        }

#pragma unroll
        for (int nt = 0; nt < 4; ++nt) {
#pragma unroll
            for (int r = 0; r < 4; ++r) {
                int q = q0 + quad * 4 + r;
                if (q < TT)
                    o[((size_t)(b * TT + q)) * N_EMBD + h * 64 + nt * 16 + ln] =
                        f2bf(of[nt][r] * linv[r]);
            }
        }
    }
}

// ---------------------------------------------------------------------------
// Tokenizer helpers
// ---------------------------------------------------------------------------
__global__ __launch_bounds__(256) void patchify_kernel(const float* __restrict__ images,
                                                       u16* __restrict__ P) {
    int idx = blockIdx.x * 256 + threadIdx.x;  // 36864*192 exact
    int col = idx % 192, row = idx / 192;
    int p = row % 144, bt = row / 144;
    int c = col % 3, pp = col / 3;
    int pw = pp & 7, ph = pp >> 3;
    int hp = p / 12, wp = p % 12;
    float v = images[(((size_t)bt * 3 + c) * 96 + hp * 8 + ph) * 96 + wp * 8 + pw];
    P[idx] = f2bf(v);
}

__global__ __launch_bounds__(256) void img_scatter_kernel(const float* __restrict__ imgtok,
                                                          const float* __restrict__ temb,
                                                          const float* __restrict__ pos,
                                                          float* __restrict__ xw) {
    int idx = blockIdx.x * 256 + threadIdx.x;  // 36864*384 exact
    int n = idx % 384, row = idx / 384;
    int p = row % 144, bt = row / 144;
    int t = bt & 1, b = bt >> 1;
    int tok = t * 145 + 1 + p;
    xw[((size_t)b * TT + tok) * N_EMBD + n] =
        imgtok[idx] + temb[t * N_EMBD + n] + pos[(size_t)tok * N_EMBD + n];
}

__global__ __launch_bounds__(384) void st_kernel(const float* __restrict__ state,
                                                 const float* __restrict__ w1,
                                                 const float* __restrict__ b1,
                                                 const float* __restrict__ w2,
                                                 const float* __restrict__ b2,
                                                 const float* __restrict__ temb,
                                                 const float* __restrict__ pos,
                                                 float* __restrict__ xw) {
    int bt = blockIdx.x;
    int t = bt & 1, b = bt >> 1;
    int n = threadIdx.x;
    float s0 = state[bt * 2], s1 = state[bt * 2 + 1];
    float acc = b2[n];
#pragma unroll
    for (int j = 0; j < 32; ++j) {
        float hh = fmaxf(s0 * w1[j] + s1 * w1[32 + j] + b1[j], 0.f);
        acc += hh * w2[j * N_EMBD + n];
    }
    int tok = t * 145;
    xw[((size_t)b * TT + tok) * N_EMBD + n] =
        acc + temb[t * N_EMBD + n] + pos[(size_t)tok * N_EMBD + n];
}

__global__ __launch_bounds__(256) void ro_kernel(const float* __restrict__ readout,
                                                 const float* __restrict__ pos,
                                                 float* __restrict__ xw) {
    int idx = blockIdx.x * 256 + threadIdx.x;  // 128*384 exact
    int n = idx % 384, b = idx / 384;
    xw[((size_t)b * TT + 290) * N_EMBD + n] = readout[n] + pos[(size_t)290 * N_EMBD + n];
}

// ---------------------------------------------------------------------------
// Workspace layout (all offsets 256B-aligned). TOTAL = 175,325,184 B (~167 MB)
// ---------------------------------------------------------------------------
extern "C" void kernel_launch(void* const* d_in, const int* in_sizes, int n_in,
                              void* d_out, int out_size, void* d_ws, size_t ws_size,
                              hipStream_t stream) {
    const float* images   = (const float*)d_in[0];
    const float* state    = (const float*)d_in[1];
    const float* img_w    = (const float*)d_in[2];
    const float* img_b    = (const float*)d_in[3];
    const float* img_temb = (const float*)d_in[4];
    const float* st_w1    = (const float*)d_in[5];
    const float* st_b1    = (const float*)d_in[6];
    const float* st_w2    = (const float*)d_in[7];
    const float* st_b2    = (const float*)d_in[8];
    const float* st_temb  = (const float*)d_in[9];
    const float* readout  = (const float*)d_in[10];
    const float* pos      = (const float*)d_in[11];
    const float* ln1_w    = (const float*)d_in[12];
    const float* ln1_b    = (const float*)d_in[13];
    const float* attn_w   = (const float*)d_in[14];
    const float* attn_b   = (const float*)d_in[15];
    const float* proj_w   = (const float*)d_in[16];
    const float* proj_b   = (const float*)d_in[17];
    const float* ln2_w    = (const float*)d_in[18];
    const float* ln2_b    = (const float*)d_in[19];
    const float* fc_w     = (const float*)d_in[20];
    const float* fc_b     = (const float*)d_in[21];
    const float* fc2_w    = (const float*)d_in[22];
    const float* fc2_b    = (const float*)d_in[23];
    const float* lnf_w    = (const float*)d_in[24];
    const float* lnf_b    = (const float*)d_in[25];

    char* ws = (char*)d_ws;
    float* XW   = (float*)(ws);
    u16*   Y    = (u16*)(ws + 57212928ull);       // also O (attn output)
    u16*   SH   = (u16*)(ws + 85819392ull);       // QKV | setup
    u16*   QKV  = SH;
    u16*   P    = SH;                              // setup: patches [36864,192]
    float* IMGT = (float*)(ws + 85819392ull + 14155776ull);  // setup: [36864,384] f32
    u16*   WQKVl  = (u16*)(ws + 171638784ull);    // [1152][384]
    u16*   WPROJl = (u16*)(ws + 172523520ull);    // [384][384]
    u16*   WFCl   = (u16*)(ws + 172818432ull);    // [1536][384]
    u16*   WFC2Tl = (u16*)(ws + 173998080ull);    // [384][1536]
    u16*   WIMG   = (u16*)(ws + 175177728ull);    // [384][192]

    // ---- tokenizers -> XW [128*291, 384] f32 ----
    transpose_cvt<<<dim3(12, 6), 256, 0, stream>>>(img_w, WIMG, 192, 384);
    patchify_kernel<<<27648, 256, 0, stream>>>(images, P);
    gemm_bt<3><<<dim3(3, 288), 256, 0, stream>>>(P, WIMG, 192, img_b, IMGT, nullptr, 384, 192);
    img_scatter_kernel<<<55296, 256, 0, stream>>>(IMGT, img_temb, pos, XW);
    st_kernel<<<256, 384, 0, stream>>>(state, st_w1, st_b1, st_w2, st_b2, st_temb, pos, XW);
    ro_kernel<<<192, 256, 0, stream>>>(readout, pos, XW);

    // ---- transformer layers (M = 37248 = 128*291 = 64*582) ----
    for (int l = 0; l < 12; ++l) {
        transpose_layer<<<1728, 256, 0, stream>>>(attn_w, proj_w, fc_w, fc2_w,
                                                  WQKVl, WPROJl, WFCl, WFC2Tl, l);
        ln_kernel<true><<<9312, 256, 0, stream>>>(XW, ln1_w + l * 384, ln1_b + l * 384, Y, 1, 0, 37248);
        gemm_bt<0><<<dim3(9, 291), 256, 0, stream>>>(Y, WQKVl, 384, attn_b + l * 1152,
                                                     QKV, nullptr, 1152, 384);
        attn_mfma<<<dim3(6, 128), 256, 0, stream>>>(QKV, Y);   // O aliases Y
        gemm_bt<2><<<dim3(3, 291), 256, 0, stream>>>(Y, WPROJl, 384, proj_b + l * 384,
                                                     XW, XW, 384, 384);
        ln_kernel<true><<<9312, 256, 0, stream>>>(XW, ln2_w + l * 384, ln2_b + l * 384, Y, 1, 0, 37248);
        fc_fused<<<582, 256, 0, stream>>>(Y, WFCl, fc_b + l * 1536,
                                          WFC2Tl, fc2_b + l * 384, XW);
    }
    // final LN on readout rows -> d_out [128, 384] f32
    ln_kernel<false><<<32, 256, 0, stream>>>(XW, lnf_w, lnf_b, d_out, TT, 290, 128);
}

// Round 7
// 5245.247 us; speedup vs baseline: 1.4983x; 1.4696x over previous
//
#include <hip/hip_runtime.h>

typedef unsigned short u16;
typedef unsigned int u32;

typedef __bf16 bf16x8 __attribute__((ext_vector_type(8)));
typedef float  f32x4  __attribute__((ext_vector_type(4)));

#define N_EMBD 384
#define TT     291
#define NB     128

__device__ __forceinline__ u16 f2bf(float x) {
    union { float f; u32 u; } v; v.f = x;
    u32 r = v.u + 0x7FFFu + ((v.u >> 16) & 1u);
    return (u16)(r >> 16);
}
__device__ __forceinline__ float bfl(u32 u) { return __uint_as_float(u << 16); }
__device__ __forceinline__ float bfh(u32 u) { return __uint_as_float(u & 0xFFFF0000u); }

__device__ __forceinline__ float gelu_f(float x) {
    float u = 0.7978845608028654f * x * (1.f + 0.044715f * x * x);
    float e = __expf(2.f * u);
    float t = 1.f - 2.f / (e + 1.f);   // tanh(u), safe at +-inf
    return 0.5f * x * (1.f + t);
}

// async global->LDS DMA, 16B per lane. LDS dest must be wave-uniform base +
// lane*16 in lane order (m104/m108) — caller guarantees the mapping.
__device__ __forceinline__ void load16_lds(const u16* g, u16* l) {
    __builtin_amdgcn_global_load_lds(
        (const __attribute__((address_space(1))) u32*)g,
        (__attribute__((address_space(3))) u32*)l, 16, 0, 0);
}

// ---------------------------------------------------------------------------
// 32x32 transpose+convert tile body: out[c0+rr][r0+cc] = in[r0+cc][c0+rr]
// ---------------------------------------------------------------------------
__device__ __forceinline__ void tr_tile(const float* __restrict__ src,
                                        u16* __restrict__ dst,
                                        int R, int C, int r0, int c0, int tid) {
    __shared__ float tile[32][33];
    int cc = tid & 31, rr0 = tid >> 5;
#pragma unroll
    for (int s = 0; s < 4; ++s) {
        int rr = rr0 + s * 8;
        tile[rr][cc] = src[(size_t)(r0 + rr) * C + c0 + cc];
    }
    __syncthreads();
#pragma unroll
    for (int s = 0; s < 4; ++s) {
        int rr = rr0 + s * 8;
        dst[(size_t)(c0 + rr) * R + (r0 + cc)] = f2bf(tile[cc][rr]);
    }
}

// generic: in[R][C] f32 -> out[C][R] bf16, grid (C/32, R/32)
__global__ __launch_bounds__(256) void transpose_cvt(const float* __restrict__ in,
                                                     u16* __restrict__ out, int R, int C) {
    tr_tile(in, out, R, C, blockIdx.y * 32, blockIdx.x * 32, threadIdx.x);
}

// fused per-layer weight transpose: all 4 matrices of layer l, grid 1728
__global__ __launch_bounds__(256) void transpose_layer(const float* __restrict__ attn_w,
                                                       const float* __restrict__ proj_w,
                                                       const float* __restrict__ fc_w,
                                                       const float* __restrict__ fc2_w,
                                                       u16* __restrict__ wqkv,
                                                       u16* __restrict__ wproj,
                                                       u16* __restrict__ wfc,
                                                       u16* __restrict__ wfc2t,
                                                       int l) {
    int t = blockIdx.x;
    const float* src; u16* dst; int R, C, tx, ty;
    if (t < 432)       { int i = t;        src = attn_w + (size_t)l * 384 * 1152; dst = wqkv;  R = 384;  C = 1152; tx = i % 36; ty = i / 36; }
    else if (t < 576)  { int i = t - 432;  src = proj_w + (size_t)l * 384 * 384;  dst = wproj; R = 384;  C = 384;  tx = i % 12; ty = i / 12; }
    else if (t < 1152) { int i = t - 576;  src = fc_w   + (size_t)l * 384 * 1536; dst = wfc;   R = 384;  C = 1536; tx = i % 48; ty = i / 48; }
    else               { int i = t - 1152; src = fc2_w  + (size_t)l * 1536 * 384; dst = wfc2t; R = 1536; C = 384;  tx = i % 12; ty = i / 12; }
    tr_tile(src, dst, R, C, ty * 32, tx * 32, threadIdx.x);
}

// ---------------------------------------------------------------------------
// bf16 MFMA GEMM:  C[M,N] = A[M,K] @ B[K,N]
// A row-major bf16 (row stride K), BT row-major bf16 [N][ldb] (B^T slice).
// Tile 128x128, BK=64, 256 threads (4 waves = 2x2 of 64x64, each 4x4 MFMA).
// LDS: unpadded [128][64] via global_load_lds, with 3-bit XOR col-group
// swizzle (slot = cg ^ (row&7)) applied at BOTH stage-source and frag-read:
// makes ds_read_b128 frag reads bank-conflict-free (8 distinct bank-starts
// per 8-lane phase) where the unswizzled [128][32] layout was 4-way aliased
// (SQ_LDS_BANK_CONFLICT evidence R3/R5/R6). BK=64 also halves barrier count.
// K must be a multiple of 64.
// MODE 0: out bf16 = acc+bias        MODE 1: out bf16 = gelu(acc+bias)
// MODE 2: out f32  = resid+acc+bias  MODE 3: out f32  = acc+bias
// out row stride = N. grid (N/128, M/128)
// ---------------------------------------------------------------------------
template<int MODE>
__global__ __launch_bounds__(256) void gemm_bt(const u16* __restrict__ A,
                                               const u16* __restrict__ BT, int ldb,
                                               const float* __restrict__ bias,
                                               void* __restrict__ out,
                                               const float* __restrict__ resid,
                                               int N, int K) {
    __shared__ u16 As[128 * 64];   // 16 KB
    __shared__ u16 Bs[128 * 64];   // 16 KB
    int tid = threadIdx.x;
    int lane = tid & 63, wave = tid >> 6;
    int wr = wave >> 1, wc = wave & 1;
    const u16* Ab = A  + (size_t)blockIdx.y * 128 * K;
    const u16* Bb = BT + (size_t)blockIdx.x * 128 * ldb;

    f32x4 acc[4][4];
#pragma unroll
    for (int i = 0; i < 4; ++i)
#pragma unroll
        for (int j = 0; j < 4; ++j)
#pragma unroll
            for (int r = 0; r < 4; ++r) acc[i][j][r] = 0.f;

    int r16  = lane & 15;
    int quad = lane >> 4;
    int sw   = r16 & 7;

    // staging map: seg in [0,1024), 16B each; row = seg>>3, LDS slot cg = seg&7
    // holds global col-group (seg&7) ^ (row&7).
    int srow[4], scol[4];
#pragma unroll
    for (int s = 0; s < 4; ++s) {
        int seg = s * 256 + tid;
        srow[s] = seg >> 3;
        scol[s] = (((seg & 7) ^ (srow[s] & 7)) << 3);
    }

    for (int kt = 0; kt < K; kt += 64) {
#pragma unroll
        for (int s = 0; s < 4; ++s) {
            int seg = s * 256 + tid;
            load16_lds(Ab + (size_t)srow[s] * K   + kt + scol[s], &As[seg * 8]);
            load16_lds(Bb + (size_t)srow[s] * ldb + kt + scol[s], &Bs[seg * 8]);
        }
        __syncthreads();
#pragma unroll
        for (int kk = 0; kk < 2; ++kk) {     // k-offsets 0, 32 within the 64-slice
            bf16x8 af[4], bff[4];
#pragma unroll
            for (int i = 0; i < 4; ++i) {
                int cg = ((kk * 4 + quad) ^ sw) << 3;
                af[i]  = *(const bf16x8*)&As[(wr * 64 + i * 16 + r16) * 64 + cg];
                bff[i] = *(const bf16x8*)&Bs[(wc * 64 + i * 16 + r16) * 64 + cg];
            }
#pragma unroll
            for (int i = 0; i < 4; ++i)
#pragma unroll
                for (int j = 0; j < 4; ++j)
                    acc[i][j] = __builtin_amdgcn_mfma_f32_16x16x32_bf16(af[i], bff[j], acc[i][j], 0, 0, 0);
        }
        __syncthreads();
    }

    int rbase = (lane >> 4) * 4;
#pragma unroll
    for (int i = 0; i < 4; ++i) {
#pragma unroll
        for (int j = 0; j < 4; ++j) {
            int gr0 = blockIdx.y * 128 + wr * 64 + i * 16 + rbase;
            int gc  = blockIdx.x * 128 + wc * 64 + j * 16 + (lane & 15);
            float bj = bias ? bias[gc] : 0.f;
#pragma unroll
            for (int r = 0; r < 4; ++r) {
                size_t idx = (size_t)(gr0 + r) * N + gc;
                float v = acc[i][j][r] + bj;
                if (MODE == 0)      ((u16*)out)[idx] = f2bf(v);
                else if (MODE == 1) ((u16*)out)[idx] = f2bf(gelu_f(v));
                else if (MODE == 2) ((float*)out)[idx] = resid[idx] + v;
                else                ((float*)out)[idx] = v;
            }
        }
    }
}

// ---------------------------------------------------------------------------
// LayerNorm: rows of 384 f32 -> 384 (bf16 or f32). block 256 = 4 waves,
// one row per wave. input row = row*inRowMul + inRowAdd, output row = row
// ---------------------------------------------------------------------------
template<bool BF16OUT>
__global__ __launch_bounds__(256) void ln_kernel(const float* __restrict__ x,
                                                 const float* __restrict__ w,
                                                 const float* __restrict__ b,
                                                 void* __restrict__ yout,
                                                 int inRowMul, int inRowAdd, int nRows) {
    int row = blockIdx.x * 4 + (threadIdx.x >> 6);
    if (row >= nRows) return;
    const float* xr = x + ((size_t)row * inRowMul + inRowAdd) * N_EMBD;
    int lane = threadIdx.x & 63;
    float v[6], s = 0.f, s2 = 0.f;
#pragma unroll
    for (int i = 0; i < 6; ++i) {
        v[i] = xr[lane + 64 * i];
        s += v[i]; s2 += v[i] * v[i];
    }
#pragma unroll
    for (int off = 32; off > 0; off >>= 1) {
        s  += __shfl_down(s, off);
        s2 += __shfl_down(s2, off);
    }
    float mean = __shfl(s, 0) * (1.f / 384.f);
    float var  = __shfl(s2, 0) * (1.f / 384.f) - mean * mean;
    float rs = rsqrtf(var + 1e-5f);
#pragma unroll
    for (int i = 0; i < 6; ++i) {
        int c = lane + 64 * i;
        float o = (v[i] - mean) * rs * w[c] + b[c];
        if (BF16OUT) ((u16*)yout)[(size_t)row * N_EMBD + c] = f2bf(o);
        else         ((float*)yout)[(size_t)row * N_EMBD + c] = o;
    }
}

// ---------------------------------------------------------------------------
// MFMA attention. One block (256 thr, 4 waves) per (head, batch).
// qkv bf16 [B*291, 1152] -> o bf16 [B*291, 384].
// Full-row softmax (S=291 -> 19 k-tiles of 16 held in 19 C-frags/wave).
// Rows 0..289 attend to all 291 keys; row 290 attends only to itself.
// ---------------------------------------------------------------------------
__global__ __launch_bounds__(256) void attn_mfma(const u16* __restrict__ qkv,
                                                 u16* __restrict__ o) {
    __shared__ u16 Ks[304][72];
    __shared__ u16 Vt[64][344];
    __shared__ u16 Ps[4][16][344];
    int h = blockIdx.x, b = blockIdx.y;
    int tid = threadIdx.x;
    int lane = tid & 63, wave = tid >> 6;
    int ln = lane & 15, quad = lane >> 4;
    const u16* base = qkv + (size_t)b * TT * 1152;

    // ---- stage K rows 0..290 (+zero pad rows 291..303) ----
    for (int slot = tid; slot < 304 * 8; slot += 256) {
        int row = slot >> 3, seg = slot & 7;
        uint4 v = make_uint4(0, 0, 0, 0);
        if (row < TT) v = *(const uint4*)(base + (size_t)row * 1152 + 384 + h * 64 + seg * 8);
        *(uint4*)&Ks[row][seg * 8] = v;
    }
    // ---- stage V transposed: Vt[d][key] ----
    for (int slot = tid; slot < TT * 8; slot += 256) {
        int dg = slot / TT, k = slot - dg * TT;
        uint4 v = *(const uint4*)(base + (size_t)k * 1152 + 768 + h * 64 + dg * 8);
        const u16* pv = (const u16*)&v;
#pragma unroll
        for (int j = 0; j < 8; ++j) Vt[dg * 8 + j][k] = pv[j];
    }
    // zero pad cols 291..319 of Vt
    for (int slot = tid; slot < 64 * 32; slot += 256) {
        int d = slot >> 5, c = 288 + (slot & 31);
        if (c >= TT && c < 320) Vt[d][c] = 0;
    }
    __syncthreads();

    // ---- per-wave Q-tiles ----
    for (int qt = wave; qt < 19; qt += 4) {
        int q0 = qt * 16;
        int qrow = q0 + ln; if (qrow > TT - 1) qrow = TT - 1;
        const u16* qp = base + (size_t)qrow * 1152 + h * 64;
        bf16x8 qf0 = *(const bf16x8*)(qp + quad * 8);
        bf16x8 qf1 = *(const bf16x8*)(qp + 32 + quad * 8);

        f32x4 sc[19];
#pragma unroll
        for (int kt = 0; kt < 19; ++kt) {
            bf16x8 kb0 = *(const bf16x8*)&Ks[kt * 16 + ln][quad * 8];
            bf16x8 kb1 = *(const bf16x8*)&Ks[kt * 16 + ln][32 + quad * 8];
            f32x4 z = {0.f, 0.f, 0.f, 0.f};
            z = __builtin_amdgcn_mfma_f32_16x16x32_bf16(qf0, kb0, z, 0, 0, 0);
            sc[kt] = __builtin_amdgcn_mfma_f32_16x16x32_bf16(qf1, kb1, z, 0, 0, 0);
        }

        float linv[4];
#pragma unroll
        for (int r = 0; r < 4; ++r) {
            int q = q0 + quad * 4 + r;
            float m = -1e30f;
#pragma unroll
            for (int kt = 0; kt < 19; ++kt) {
                int key = kt * 16 + ln;
                float s = sc[kt][r] * 0.125f;
                bool ok = (key < TT) && (q != TT - 1 || key == TT - 1);
                s = ok ? s : -1e30f;
                sc[kt][r] = s;
                m = fmaxf(m, s);
            }
            m = fmaxf(m, __shfl_xor(m, 1));
            m = fmaxf(m, __shfl_xor(m, 2));
            m = fmaxf(m, __shfl_xor(m, 4));
            m = fmaxf(m, __shfl_xor(m, 8));
            float l = 0.f;
#pragma unroll
            for (int kt = 0; kt < 19; ++kt) {
                float p = __expf(sc[kt][r] - m);
                sc[kt][r] = p;
                l += p;
            }
            l += __shfl_xor(l, 1);
            l += __shfl_xor(l, 2);
            l += __shfl_xor(l, 4);
            l += __shfl_xor(l, 8);
            linv[r] = 1.f / l;
        }

#pragma unroll
        for (int kt = 0; kt < 19; ++kt) {
#pragma unroll
            for (int r = 0; r < 4; ++r)
                Ps[wave][quad * 4 + r][kt * 16 + ln] = f2bf(sc[kt][r]);
        }
#pragma unroll
        for (int r = 0; r < 4; ++r) Ps[wave][quad * 4 + r][304 + ln] = 0;

        f32x4 of[4];
#pragma unroll
        for (int nt = 0; nt < 4; ++nt)
#pragma unroll
            for (int r = 0; r < 4; ++r) of[nt][r] = 0.f;
#pragma unroll
        for (int kt2 = 0; kt2 < 10; ++kt2) {
            bf16x8 pa = *(const bf16x8*)&Ps[wave][ln][kt2 * 32 + quad * 8];
#pragma unroll
            for (int nt = 0; nt < 4; ++nt) {
                bf16x8 vb = *(const bf16x8*)&Vt[nt * 16 + ln][kt2 * 32 + quad * 8];
                of[nt] = __builtin_amdgcn_mfma_f32_16x16x32_bf16(pa, vb, of[nt], 0, 0, 0);
            }
        }

#pragma unroll
        for (int nt = 0; nt < 4; ++nt) {
#pragma unroll
            for (int r = 0; r < 4; ++r) {
                int q = q0 + quad * 4 + r;
                if (q < TT)
                    o[((size_t)(b * TT + q)) * N_EMBD + h * 64 + nt * 16 + ln] =
                        f2bf(of[nt][r] * linv[r]);
            }
        }
    }
}

// ---------------------------------------------------------------------------
// Tokenizer helpers
// ---------------------------------------------------------------------------
__global__ __launch_bounds__(256) void patchify_kernel(const float* __restrict__ images,
                                                       u16* __restrict__ P) {
    int idx = blockIdx.x * 256 + threadIdx.x;  // 36864*192 exact
    int col = idx % 192, row = idx / 192;
    int p = row % 144, bt = row / 144;
    int c = col % 3, pp = col / 3;
    int pw = pp & 7, ph = pp >> 3;
    int hp = p / 12, wp = p % 12;
    float v = images[(((size_t)bt * 3 + c) * 96 + hp * 8 + ph) * 96 + wp * 8 + pw];
    P[idx] = f2bf(v);
}

__global__ __launch_bounds__(256) void img_scatter_kernel(const float* __restrict__ imgtok,
                                                          const float* __restrict__ temb,
                                                          const float* __restrict__ pos,
                                                          float* __restrict__ xw) {
    int idx = blockIdx.x * 256 + threadIdx.x;  // 36864*384 exact
    int n = idx % 384, row = idx / 384;
    int p = row % 144, bt = row / 144;
    int t = bt & 1, b = bt >> 1;
    int tok = t * 145 + 1 + p;
    xw[((size_t)b * TT + tok) * N_EMBD + n] =
        imgtok[idx] + temb[t * N_EMBD + n] + pos[(size_t)tok * N_EMBD + n];
}

__global__ __launch_bounds__(384) void st_kernel(const float* __restrict__ state,
                                                 const float* __restrict__ w1,
                                                 const float* __restrict__ b1,
                                                 const float* __restrict__ w2,
                                                 const float* __restrict__ b2,
                                                 const float* __restrict__ temb,
                                                 const float* __restrict__ pos,
                                                 float* __restrict__ xw) {
    int bt = blockIdx.x;
    int t = bt & 1, b = bt >> 1;
    int n = threadIdx.x;
    float s0 = state[bt * 2], s1 = state[bt * 2 + 1];
    float acc = b2[n];
#pragma unroll
    for (int j = 0; j < 32; ++j) {
        float hh = fmaxf(s0 * w1[j] + s1 * w1[32 + j] + b1[j], 0.f);
        acc += hh * w2[j * N_EMBD + n];
    }
    int tok = t * 145;
    xw[((size_t)b * TT + tok) * N_EMBD + n] =
        acc + temb[t * N_EMBD + n] + pos[(size_t)tok * N_EMBD + n];
}

__global__ __launch_bounds__(256) void ro_kernel(const float* __restrict__ readout,
                                                 const float* __restrict__ pos,
                                                 float* __restrict__ xw) {
    int idx = blockIdx.x * 256 + threadIdx.x;  // 128*384 exact
    int n = idx % 384, b = idx / 384;
    xw[((size_t)b * TT + 290) * N_EMBD + n] = readout[n] + pos[(size_t)290 * N_EMBD + n];
}

// ---------------------------------------------------------------------------
// Workspace layout (all offsets 256B-aligned). TOTAL = 175,325,184 B (~167 MB)
// ---------------------------------------------------------------------------
extern "C" void kernel_launch(void* const* d_in, const int* in_sizes, int n_in,
                              void* d_out, int out_size, void* d_ws, size_t ws_size,
                              hipStream_t stream) {
    const float* images   = (const float*)d_in[0];
    const float* state    = (const float*)d_in[1];
    const float* img_w    = (const float*)d_in[2];
    const float* img_b    = (const float*)d_in[3];
    const float* img_temb = (const float*)d_in[4];
    const float* st_w1    = (const float*)d_in[5];
    const float* st_b1    = (const float*)d_in[6];
    const float* st_w2    = (const float*)d_in[7];
    const float* st_b2    = (const float*)d_in[8];
    const float* st_temb  = (const float*)d_in[9];
    const float* readout  = (const float*)d_in[10];
    const float* pos      = (const float*)d_in[11];
    const float* ln1_w    = (const float*)d_in[12];
    const float* ln1_b    = (const float*)d_in[13];
    const float* attn_w   = (const float*)d_in[14];
    const float* attn_b   = (const float*)d_in[15];
    const float* proj_w   = (const float*)d_in[16];
    const float* proj_b   = (const float*)d_in[17];
    const float* ln2_w    = (const float*)d_in[18];
    const float* ln2_b    = (const float*)d_in[19];
    const float* fc_w     = (const float*)d_in[20];
    const float* fc_b     = (const float*)d_in[21];
    const float* fc2_w    = (const float*)d_in[22];
    const float* fc2_b    = (const float*)d_in[23];
    const float* lnf_w    = (const float*)d_in[24];
    const float* lnf_b    = (const float*)d_in[25];

    char* ws = (char*)d_ws;
    float* XW   = (float*)(ws);
    u16*   Y    = (u16*)(ws + 57212928ull);       // also O (attn output)
    u16*   SH   = (u16*)(ws + 85819392ull);       // QKV | G | setup
    u16*   QKV  = SH;
    u16*   G    = SH;
    u16*   P    = SH;                              // setup: patches [36864,192]
    float* IMGT = (float*)(ws + 85819392ull + 14155776ull);  // setup: [36864,384] f32
    u16*   WQKVl  = (u16*)(ws + 171638784ull);    // [1152][384]
    u16*   WPROJl = (u16*)(ws + 172523520ull);    // [384][384]
    u16*   WFCl   = (u16*)(ws + 172818432ull);    // [1536][384]
    u16*   WFC2Tl = (u16*)(ws + 173998080ull);    // [384][1536]
    u16*   WIMG   = (u16*)(ws + 175177728ull);    // [384][192]

    // ---- tokenizers -> XW [128*291, 384] f32 ----
    transpose_cvt<<<dim3(12, 6), 256, 0, stream>>>(img_w, WIMG, 192, 384);
    patchify_kernel<<<27648, 256, 0, stream>>>(images, P);
    gemm_bt<3><<<dim3(3, 288), 256, 0, stream>>>(P, WIMG, 192, img_b, IMGT, nullptr, 384, 192);
    img_scatter_kernel<<<55296, 256, 0, stream>>>(IMGT, img_temb, pos, XW);
    st_kernel<<<256, 384, 0, stream>>>(state, st_w1, st_b1, st_w2, st_b2, st_temb, pos, XW);
    ro_kernel<<<192, 256, 0, stream>>>(readout, pos, XW);

    // ---- transformer layers (M = 37248 = 128*291) ----
    for (int l = 0; l < 12; ++l) {
        transpose_layer<<<1728, 256, 0, stream>>>(attn_w, proj_w, fc_w, fc2_w,
                                                  WQKVl, WPROJl, WFCl, WFC2Tl, l);
        ln_kernel<true><<<9312, 256, 0, stream>>>(XW, ln1_w + l * 384, ln1_b + l * 384, Y, 1, 0, 37248);
        gemm_bt<0><<<dim3(9, 291), 256, 0, stream>>>(Y, WQKVl, 384, attn_b + l * 1152,
                                                     QKV, nullptr, 1152, 384);
        attn_mfma<<<dim3(6, 128), 256, 0, stream>>>(QKV, Y);   // O aliases Y
        gemm_bt<2><<<dim3(3, 291), 256, 0, stream>>>(Y, WPROJl, 384, proj_b + l * 384,
                                                     XW, XW, 384, 384);
        ln_kernel<true><<<9312, 256, 0, stream>>>(XW, ln2_w + l * 384, ln2_b + l * 384, Y, 1, 0, 37248);
        // MLP in two 768-wide halves so G fits in the QKV region
        gemm_bt<1><<<dim3(6, 291), 256, 0, stream>>>(Y, WFCl, 384, fc_b + l * 1536,
                                                     G, nullptr, 768, 384);
        gemm_bt<2><<<dim3(3, 291), 256, 0, stream>>>(G, WFC2Tl, 1536, nullptr,
                                                     XW, XW, 384, 768);
        gemm_bt<1><<<dim3(6, 291), 256, 0, stream>>>(Y, WFCl + 768 * 384, 384,
                                                     fc_b + l * 1536 + 768, G, nullptr, 768, 384);
        gemm_bt<2><<<dim3(3, 291), 256, 0, stream>>>(G, WFC2Tl + 768, 1536, fc2_b + l * 384,
                                                     XW, XW, 384, 768);
    }
    // final LN on readout rows -> d_out [128, 384] f32
    ln_kernel<false><<<32, 256, 0, stream>>>(XW, lnf_w, lnf_b, d_out, TT, 290, 128);
}